// Round 1
// baseline (1441.758 us; speedup 1.0000x reference)
//
#include <hip/hip_runtime.h>
#include <math.h>

// ---------------------------------------------------------------------------
// TemporalUnitRolloutV341 — GRU rollout, 32 steps over 2048 rows of D=512.
// Round 1: algebraic hoist (G0/Tg/P_sem/c1/c2) + bf16 MFMA GEMMs (fp32 acc,
// fp32 recurrent state), 4 kernels/step.
// ---------------------------------------------------------------------------

typedef unsigned short u16;
using bf16x8 = __attribute__((ext_vector_type(8))) short;
using f32x4  = __attribute__((ext_vector_type(4))) float;

#define DEV __device__ __forceinline__

constexpr int D   = 512;
constexpr int D3  = 1536;
constexpr int H   = 32;
constexpr int BU  = 2048;
constexpr long long OUT_HALF = (long long)BU * H * D;  // 33554432

DEV u16 f2bf(float x){
  union { float f; unsigned u; } c; c.f = x;
  unsigned u = c.u;
  u += 0x7fffu + ((u >> 16) & 1u);
  return (u16)(u >> 16);
}

DEV void gload_lds16(const void* g, void* l){
  __builtin_amdgcn_global_load_lds(
      (const __attribute__((address_space(1))) void*)g,
      (__attribute__((address_space(3))) void*)l, 16, 0, 0);
}

DEV f32x4 mfma16(bf16x8 a, bf16x8 b, f32x4 c){
  return __builtin_amdgcn_mfma_f32_16x16x32_bf16(a, b, c, 0, 0, 0);
}

DEV float sigm(float x){ return 1.f / (1.f + expf(-x)); }

// ---------------------------------------------------------------------------
// Setup: bf16 weight conversions, folded scale matrices, c1/c2, Tg table,
// initial state. Grid covers 2048*512 = 1,048,576 threads.
// ---------------------------------------------------------------------------
__global__ __launch_bounds__(256) void prep_kernel(
    const float* __restrict__ z_dyn, const float* __restrict__ z_sem,
    const float* __restrict__ te_w,  const float* __restrict__ w_ih,
    const float* __restrict__ w_hh,  const float* __restrict__ ln2_g,
    const float* __restrict__ ln2_b, const float* __restrict__ w1,
    const float* __restrict__ b1,    const float* __restrict__ w2,
    float* __restrict__ h, u16* __restrict__ hbf0, u16* __restrict__ sem_bf,
    u16* __restrict__ wih_bf, u16* __restrict__ whh_bf,
    u16* __restrict__ W1s, u16* __restrict__ W1h, u16* __restrict__ w2bf,
    float* __restrict__ c1, float* __restrict__ c2p, float* __restrict__ Tg)
{
  int i = blockIdx.x * 256 + threadIdx.x;
  if (i < BU * D) {
    float hv = z_dyn[i];
    h[i] = hv;
    hbf0[i] = f2bf(hv);
    sem_bf[i] = f2bf(z_sem[i]);
  }
  if (i < D3 * D) {
    wih_bf[i] = f2bf(w_ih[i]);
    whh_bf[i] = f2bf(w_hh[i]);
  }
  if (i < D * D) {
    int k = i >> 9, j = i & 511;
    W1s[i]  = f2bf(w1[k * 1024 + j] * ln2_g[j]);
    W1h[i]  = f2bf(w1[k * 1024 + 512 + j] * ln2_g[512 + j]);
    w2bf[i] = f2bf(w2[i]);
  }
  if (i < D) {
    float s1 = 0.f, s2 = 0.f;
    for (int j = 0; j < 1024; ++j) {
      float w = w1[i * 1024 + j];
      s1 += w * ln2_g[j];
      s2 += w * ln2_b[j];
    }
    c1[i] = s1;
    c2p[i] = s2 + b1[i];
  }
  if (i < H * D3) {
    int t = i / D3, c = i % D3;
    float s = 0.f;
    for (int d0 = 0; d0 < D; ++d0) s += te_w[t * D + d0] * w_ih[c * D + d0];
    Tg[i] = s;
  }
}

// Per-row sums of sem and sem^2 (for the ln2 stats split). One wave per row.
__global__ __launch_bounds__(256) void rowstats_kernel(
    const float* __restrict__ sem, float* __restrict__ Ssem,
    float* __restrict__ Ssem2)
{
  const int wid = threadIdx.x >> 6, lane = threadIdx.x & 63;
  const int row = blockIdx.x * 4 + wid;
  const float* p = sem + (size_t)row * D + lane * 8;
  float4 a0 = *(const float4*)p;
  float4 a1 = *(const float4*)(p + 4);
  float s  = a0.x + a0.y + a0.z + a0.w + a1.x + a1.y + a1.z + a1.w;
  float s2 = a0.x*a0.x + a0.y*a0.y + a0.z*a0.z + a0.w*a0.w
           + a1.x*a1.x + a1.y*a1.y + a1.z*a1.z + a1.w*a1.w;
  #pragma unroll
  for (int o = 1; o < 64; o <<= 1) { s += __shfl_xor(s, o); s2 += __shfl_xor(s2, o); }
  if (lane == 0) { Ssem[row] = s; Ssem2[row] = s2; }
}

// ---------------------------------------------------------------------------
// Generic NT bf16 GEMM, 64x64 tile, K=512, 4 waves (2x2), with mode epilogue.
// MODE 0: C = A@B.T + bias          (G0)
// MODE 1: C = A@B.T                 (P_sem)
// MODE 2: hid_bf = gelu(rstd*(Psem+acc) - m*rstd*c1 + c2p)
// MODE 3: out_sems[row,t,col] = sem + acc + b2
// LDS XOR-swizzled (chunk ^= row&7) so ds_read_b128 is conflict-free;
// global_load_lds sources are inverse-swizzled (rule #21).
// ---------------------------------------------------------------------------
template<int MODE>
__global__ __launch_bounds__(256) void gemm64_kernel(
    const u16* __restrict__ A, const u16* __restrict__ Bw,
    float* __restrict__ C, int ldc, const float* __restrict__ bias,
    const float* __restrict__ Psem, const float* __restrict__ m2a,
    const float* __restrict__ rstd2a, const float* __restrict__ c1v,
    const float* __restrict__ c2pv, u16* __restrict__ hid_bf,
    const float* __restrict__ semp, const float* __restrict__ b2v,
    float* __restrict__ out_sems, int t)
{
  __shared__ __align__(16) char smem[64 * 128 + 64 * 128];
  char* As = smem;
  char* Bs = smem + 64 * 128;
  const int tid = threadIdx.x, wid = tid >> 6, lane = tid & 63;
  const int wr = wid >> 1, wc = wid & 1;
  const int row0 = blockIdx.x * 64, col0 = blockIdx.y * 64;

  f32x4 acc[2][2] = {};

  for (int kt = 0; kt < 8; ++kt) {
    __syncthreads();
    const int k0 = kt * 64;
    #pragma unroll
    for (int it = 0; it < 2; ++it) {
      int s = it * 256 + tid;
      int pr = s >> 3, pc = s & 7;
      int lch = pc ^ (pr & 7);
      gload_lds16(A + (size_t)(row0 + pr) * D + k0 + lch * 8,
                  As + (it * 256 + wid * 64) * 16);
    }
    #pragma unroll
    for (int it = 0; it < 2; ++it) {
      int s = it * 256 + tid;
      int pr = s >> 3, pc = s & 7;
      int lch = pc ^ (pr & 7);
      gload_lds16(Bw + (size_t)(col0 + pr) * D + k0 + lch * 8,
                  Bs + (it * 256 + wid * 64) * 16);
    }
    asm volatile("s_waitcnt vmcnt(0)" ::: "memory");
    __syncthreads();

    #pragma unroll
    for (int kk = 0; kk < 2; ++kk) {
      const int lc = lane & 15, hi = lane >> 4;
      const int ch = kk * 4 + hi;
      bf16x8 af[2], bfr[2];
      #pragma unroll
      for (int mi = 0; mi < 2; ++mi) {
        int r = wr * 32 + mi * 16 + lc;
        af[mi] = *(const bf16x8*)(As + r * 128 + ((ch ^ (r & 7)) << 4));
      }
      #pragma unroll
      for (int ni = 0; ni < 2; ++ni) {
        int r = wc * 32 + ni * 16 + lc;
        bfr[ni] = *(const bf16x8*)(Bs + r * 128 + ((ch ^ (r & 7)) << 4));
      }
      #pragma unroll
      for (int mi = 0; mi < 2; ++mi)
        #pragma unroll
        for (int ni = 0; ni < 2; ++ni)
          acc[mi][ni] = mfma16(af[mi], bfr[ni], acc[mi][ni]);
    }
  }

  const int lj = lane >> 4, lc2 = lane & 15;
  #pragma unroll
  for (int mi = 0; mi < 2; ++mi)
    #pragma unroll
    for (int ni = 0; ni < 2; ++ni)
      #pragma unroll
      for (int j = 0; j < 4; ++j) {
        int row = row0 + wr * 32 + mi * 16 + lj * 4 + j;
        int col = col0 + wc * 32 + ni * 16 + lc2;
        float v = acc[mi][ni][j];
        if constexpr (MODE == 0) {
          C[(size_t)row * ldc + col] = v + bias[col];
        } else if constexpr (MODE == 1) {
          C[(size_t)row * ldc + col] = v;
        } else if constexpr (MODE == 2) {
          float rs = rstd2a[row], mm = m2a[row];
          float pre = rs * (Psem[(size_t)row * D + col] + v)
                      - mm * rs * c1v[col] + c2pv[col];
          float gl = 0.5f * pre * (1.f + erff(pre * 0.70710678118654752f));
          hid_bf[(size_t)row * D + col] = f2bf(gl);
        } else {
          out_sems[((long long)row * H + t) * D + col] =
              semp[(size_t)row * D + col] + v + b2v[col];
        }
      }
}

// ---------------------------------------------------------------------------
// GRU step: gh = h@w_hh.T over three 64-col gate strips (r,z,n at the same
// local cols), fused gate math; writes h (fp32, in-place elementwise-safe)
// and bf16 snapshot for the next step's GEMM.
// ---------------------------------------------------------------------------
__global__ __launch_bounds__(256) void gru_step_kernel(
    const u16* __restrict__ hbf_in, const u16* __restrict__ whh_bf,
    const float* __restrict__ G0, const float* __restrict__ Tg,
    const float* __restrict__ b_hh, float* __restrict__ h,
    u16* __restrict__ hbf_out, int t)
{
  __shared__ __align__(16) char smem[64 * 128 + 3 * 64 * 128];  // 32 KiB
  char* As = smem;
  char* Bs = smem + 64 * 128;
  const int tid = threadIdx.x, wid = tid >> 6, lane = tid & 63;
  const int wr = wid >> 1, wc = wid & 1;
  const int row0 = blockIdx.x * 64, c0 = blockIdx.y * 64;

  f32x4 acc[2][6] = {};

  for (int kt = 0; kt < 8; ++kt) {
    __syncthreads();
    const int k0 = kt * 64;
    #pragma unroll
    for (int it = 0; it < 2; ++it) {
      int s = it * 256 + tid;
      int pr = s >> 3, pc = s & 7;
      int lch = pc ^ (pr & 7);
      gload_lds16(hbf_in + (size_t)(row0 + pr) * D + k0 + lch * 8,
                  As + (it * 256 + wid * 64) * 16);
    }
    #pragma unroll
    for (int g = 0; g < 3; ++g)
      #pragma unroll
      for (int it = 0; it < 2; ++it) {
        int s = it * 256 + tid;
        int pr = s >> 3, pc = s & 7;
        int lch = pc ^ (pr & 7);
        gload_lds16(whh_bf + (size_t)(g * D + c0 + pr) * D + k0 + lch * 8,
                    Bs + g * 8192 + (it * 256 + wid * 64) * 16);
      }
    asm volatile("s_waitcnt vmcnt(0)" ::: "memory");
    __syncthreads();

    #pragma unroll
    for (int kk = 0; kk < 2; ++kk) {
      const int lc = lane & 15, hi = lane >> 4;
      const int ch = kk * 4 + hi;
      bf16x8 af[2];
      #pragma unroll
      for (int mi = 0; mi < 2; ++mi) {
        int r = wr * 32 + mi * 16 + lc;
        af[mi] = *(const bf16x8*)(As + r * 128 + ((ch ^ (r & 7)) << 4));
      }
      #pragma unroll
      for (int g = 0; g < 3; ++g)
        #pragma unroll
        for (int ci = 0; ci < 2; ++ci) {
          int r = g * 64 + wc * 32 + ci * 16 + lc;
          bf16x8 b = *(const bf16x8*)(Bs + r * 128 + ((ch ^ (r & 7)) << 4));
          acc[0][g * 2 + ci] = mfma16(af[0], b, acc[0][g * 2 + ci]);
          acc[1][g * 2 + ci] = mfma16(af[1], b, acc[1][g * 2 + ci]);
        }
    }
  }

  const int lj = lane >> 4, lc2 = lane & 15;
  #pragma unroll
  for (int mi = 0; mi < 2; ++mi)
    #pragma unroll
    for (int ci = 0; ci < 2; ++ci)
      #pragma unroll
      for (int j = 0; j < 4; ++j) {
        int row = row0 + wr * 32 + mi * 16 + lj * 4 + j;
        int col = c0 + wc * 32 + ci * 16 + lc2;
        float ar = acc[mi][0 + ci][j];
        float az = acc[mi][2 + ci][j];
        float an = acc[mi][4 + ci][j];
        size_t g0i = (size_t)row * D3 + col;
        float gr = G0[g0i]        + Tg[t * D3 + col];
        float gz = G0[g0i + 512]  + Tg[t * D3 + 512 + col];
        float gn = G0[g0i + 1024] + Tg[t * D3 + 1024 + col];
        float r = sigm(gr + ar + b_hh[col]);
        float z = sigm(gz + az + b_hh[512 + col]);
        float n = tanhf(gn + r * (an + b_hh[1024 + col]));
        size_t hi_ = (size_t)row * D + col;
        float ho = h[hi_];
        float hn = (1.f - z) * n + z * ho;
        h[hi_] = hn;
        hbf_out[hi_] = f2bf(hn);
      }
}

// ---------------------------------------------------------------------------
// LayerNorm(h_new) -> dyn output + bf16 h_norm + ln2 stats (m2, rstd2).
// One wave per row.
// ---------------------------------------------------------------------------
__global__ __launch_bounds__(256) void ln_kernel(
    const float* __restrict__ h, const float* __restrict__ ln_g,
    const float* __restrict__ ln_b, const float* __restrict__ Ssem,
    const float* __restrict__ Ssem2, float* __restrict__ dyn_out,
    u16* __restrict__ hn_bf, float* __restrict__ m2a,
    float* __restrict__ rstd2a, int t)
{
  const int wid = threadIdx.x >> 6, lane = threadIdx.x & 63;
  const int row = blockIdx.x * 4 + wid;
  const float* hp = h + (size_t)row * D + lane * 8;
  float4 a0 = *(const float4*)hp;
  float4 a1 = *(const float4*)(hp + 4);
  float v[8] = {a0.x, a0.y, a0.z, a0.w, a1.x, a1.y, a1.z, a1.w};
  float s = 0.f, s2 = 0.f;
  #pragma unroll
  for (int k = 0; k < 8; ++k) { s += v[k]; s2 += v[k] * v[k]; }
  #pragma unroll
  for (int o = 1; o < 64; o <<= 1) { s += __shfl_xor(s, o); s2 += __shfl_xor(s2, o); }
  float m = s * (1.f / 512.f);
  float var = s2 * (1.f / 512.f) - m * m;
  float rsd = rsqrtf(var + 1e-5f);

  const float* gp = ln_g + lane * 8;
  const float* bp = ln_b + lane * 8;
  float4 g0 = *(const float4*)gp, g1 = *(const float4*)(gp + 4);
  float4 b0 = *(const float4*)bp, b1 = *(const float4*)(bp + 4);
  float gg[8] = {g0.x, g0.y, g0.z, g0.w, g1.x, g1.y, g1.z, g1.w};
  float bb[8] = {b0.x, b0.y, b0.z, b0.w, b1.x, b1.y, b1.z, b1.w};

  float hn[8];
  float sh = 0.f, sh2 = 0.f;
  #pragma unroll
  for (int k = 0; k < 8; ++k) {
    float x = (v[k] - m) * rsd * gg[k] + bb[k];
    hn[k] = x; sh += x; sh2 += x * x;
  }

  float* dp = dyn_out + ((long long)row * H + t) * D + lane * 8;
  *(float4*)dp       = make_float4(hn[0], hn[1], hn[2], hn[3]);
  *(float4*)(dp + 4) = make_float4(hn[4], hn[5], hn[6], hn[7]);

  union { u16 us[8]; uint4 u; } pk;
  #pragma unroll
  for (int k = 0; k < 8; ++k) pk.us[k] = f2bf(hn[k]);
  *(uint4*)(hn_bf + (size_t)row * D + lane * 8) = pk.u;

  #pragma unroll
  for (int o = 1; o < 64; o <<= 1) { sh += __shfl_xor(sh, o); sh2 += __shfl_xor(sh2, o); }
  if (lane == 0) {
    float m2 = (Ssem[row] + sh) * (1.f / 1024.f);
    float var2 = (Ssem2[row] + sh2) * (1.f / 1024.f) - m2 * m2;
    m2a[row] = m2;
    rstd2a[row] = rsqrtf(var2 + 1e-5f);
  }
}

// ---------------------------------------------------------------------------
extern "C" void kernel_launch(void* const* d_in, const int* in_sizes, int n_in,
                              void* d_out, int out_size, void* d_ws, size_t ws_size,
                              hipStream_t stream)
{
  (void)in_sizes; (void)n_in; (void)out_size; (void)ws_size;
  const float* z_dyn = (const float*)d_in[0];
  const float* z_sem = (const float*)d_in[1];
  const float* te_w  = (const float*)d_in[2];
  const float* w_ih  = (const float*)d_in[3];
  const float* w_hh  = (const float*)d_in[4];
  const float* b_ih  = (const float*)d_in[5];
  const float* b_hh  = (const float*)d_in[6];
  const float* ln_g  = (const float*)d_in[7];
  const float* ln_b  = (const float*)d_in[8];
  const float* ln2_g = (const float*)d_in[9];
  const float* ln2_b = (const float*)d_in[10];
  const float* w1    = (const float*)d_in[11];
  const float* b1    = (const float*)d_in[12];
  const float* w2    = (const float*)d_in[13];
  const float* b2    = (const float*)d_in[14];

  char* ws = (char*)d_ws;
  const size_t MB = 1ull << 20;
  float* h      = (float*)(ws + 0);          // 4 MB
  u16*  hbf0    = (u16*)(ws + 4 * MB);       // 2 MB
  u16*  hbf1    = (u16*)(ws + 6 * MB);       // 2 MB
  float* G0     = (float*)(ws + 8 * MB);     // 12 MB
  float* Tg     = (float*)(ws + 20 * MB);    // 192 KB
  float* Psem   = (float*)(ws + 21 * MB);    // 4 MB
  u16*  sem_bf  = (u16*)(ws + 25 * MB);      // 2 MB
  u16*  hn_bf   = (u16*)(ws + 27 * MB);      // 2 MB
  u16*  hid_bf  = (u16*)(ws + 29 * MB);      // 2 MB
  u16*  wih_bf  = (u16*)(ws + 31 * MB);      // 1.5 MB
  u16*  whh_bf  = (u16*)(ws + 33 * MB);      // 1.5 MB
  u16*  W1s     = (u16*)(ws + 35 * MB);      // 0.5 MB
  u16*  W1h     = (u16*)(ws + 36 * MB);      // 0.5 MB
  u16*  w2bf    = (u16*)(ws + 37 * MB);      // 0.5 MB
  float* c1     = (float*)(ws + 38 * MB);
  float* c2p    = (float*)(ws + 38 * MB + 4096);
  float* Ssem   = (float*)(ws + 38 * MB + 16384);
  float* Ssem2  = (float*)(ws + 38 * MB + 24576);
  float* m2a    = (float*)(ws + 38 * MB + 32768);
  float* rstd2a = (float*)(ws + 38 * MB + 40960);

  float* outp = (float*)d_out;
  float* out_dyn  = outp;
  float* out_sems = outp + OUT_HALF;

  prep_kernel<<<4096, 256, 0, stream>>>(
      z_dyn, z_sem, te_w, w_ih, w_hh, ln2_g, ln2_b, w1, b1, w2,
      h, hbf0, sem_bf, wih_bf, whh_bf, W1s, W1h, w2bf, c1, c2p, Tg);
  rowstats_kernel<<<512, 256, 0, stream>>>(z_sem, Ssem, Ssem2);

  // G0 = sem @ w_ih.T + b_ih   [2048 x 1536]
  gemm64_kernel<0><<<dim3(32, 24), 256, 0, stream>>>(
      sem_bf, wih_bf, G0, D3, b_ih,
      nullptr, nullptr, nullptr, nullptr, nullptr, nullptr,
      nullptr, nullptr, nullptr, 0);
  // P_sem = (sem*g) @ w1[:, :512].T   [2048 x 512]
  gemm64_kernel<1><<<dim3(32, 8), 256, 0, stream>>>(
      sem_bf, W1s, Psem, D, nullptr,
      nullptr, nullptr, nullptr, nullptr, nullptr, nullptr,
      nullptr, nullptr, nullptr, 0);

  for (int t = 0; t < H; ++t) {
    const u16* hin = (t & 1) ? hbf1 : hbf0;
    u16* hout      = (t & 1) ? hbf0 : hbf1;
    gru_step_kernel<<<dim3(32, 8), 256, 0, stream>>>(
        hin, whh_bf, G0, Tg, b_hh, h, hout, t);
    ln_kernel<<<512, 256, 0, stream>>>(
        h, ln_g, ln_b, Ssem, Ssem2, out_dyn, hn_bf, m2a, rstd2a, t);
    gemm64_kernel<2><<<dim3(32, 8), 256, 0, stream>>>(
        hn_bf, W1h, nullptr, D, nullptr,
        Psem, m2a, rstd2a, c1, c2p, hid_bf,
        nullptr, nullptr, nullptr, t);
    gemm64_kernel<3><<<dim3(32, 8), 256, 0, stream>>>(
        hid_bf, w2bf, nullptr, D, nullptr,
        nullptr, nullptr, nullptr, nullptr, nullptr, nullptr,
        z_sem, b2, out_sems, t);
  }
}

// Round 2
// 1153.738 us; speedup vs baseline: 1.2496x; 1.2496x over previous
//
#include <hip/hip_runtime.h>
#include <math.h>

// ---------------------------------------------------------------------------
// TemporalUnitRolloutV341 — GRU rollout, 32 steps over 2048 rows of D=512.
// R2: 32x64 tiles (512 blocks = 2/CU), double-buffered LDS with overlapped
// global_load_lds staging, LN1 fused into gru epilogue (atomic row stats) +
// LN2/dyn-write fused into the hid GEMM's A-staging. 3 dispatches/step.
// ---------------------------------------------------------------------------

typedef unsigned short u16;
using bf16x8 = __attribute__((ext_vector_type(8))) short;
using f32x4  = __attribute__((ext_vector_type(4))) float;

#define DEV __device__ __forceinline__

constexpr int D   = 512;
constexpr int D3  = 1536;
constexpr int H   = 32;
constexpr int BU  = 2048;
constexpr long long OUT_HALF = (long long)BU * H * D;

DEV u16 f2bf(float x){
  union { float f; unsigned u; } c; c.f = x;
  unsigned u = c.u;
  u += 0x7fffu + ((u >> 16) & 1u);
  return (u16)(u >> 16);
}

DEV void gload_lds16(const void* g, void* l){
  __builtin_amdgcn_global_load_lds(
      (const __attribute__((address_space(1))) void*)g,
      (__attribute__((address_space(3))) void*)l, 16, 0, 0);
}

DEV f32x4 mfma16(bf16x8 a, bf16x8 b, f32x4 c){
  return __builtin_amdgcn_mfma_f32_16x16x32_bf16(a, b, c, 0, 0, 0);
}

DEV float sigm(float x){ return 1.f / (1.f + expf(-x)); }

// ---------------------------------------------------------------------------
// Setup: bf16 conversions, folded matrices, c1/c2, Tg table, stats zeroing.
// ---------------------------------------------------------------------------
__global__ __launch_bounds__(256) void prep_kernel(
    const float* __restrict__ z_dyn, const float* __restrict__ z_sem,
    const float* __restrict__ te_w,  const float* __restrict__ w_ih,
    const float* __restrict__ w_hh,  const float* __restrict__ ln2_g,
    const float* __restrict__ ln2_b, const float* __restrict__ w1,
    const float* __restrict__ b1,    const float* __restrict__ w2,
    float* __restrict__ h, u16* __restrict__ hbf0, u16* __restrict__ sem_bf,
    u16* __restrict__ wih_bf, u16* __restrict__ whh_bf,
    u16* __restrict__ W1s, u16* __restrict__ W1h, u16* __restrict__ w2bf,
    float* __restrict__ c1, float* __restrict__ c2p, float* __restrict__ Tg,
    float* __restrict__ sumH, float* __restrict__ sumH2)
{
  int i = blockIdx.x * 256 + threadIdx.x;
  if (i < BU * D) {
    float hv = z_dyn[i];
    h[i] = hv;
    hbf0[i] = f2bf(hv);
    sem_bf[i] = f2bf(z_sem[i]);
  }
  if (i < D3 * D) {
    wih_bf[i] = f2bf(w_ih[i]);
    whh_bf[i] = f2bf(w_hh[i]);
  }
  if (i < D * D) {
    int k = i >> 9, j = i & 511;
    W1s[i]  = f2bf(w1[k * 1024 + j] * ln2_g[j]);
    W1h[i]  = f2bf(w1[k * 1024 + 512 + j] * ln2_g[512 + j]);
    w2bf[i] = f2bf(w2[i]);
  }
  if (i < D) {
    float s1 = 0.f, s2 = 0.f;
    for (int j = 0; j < 1024; ++j) {
      float w = w1[i * 1024 + j];
      s1 += w * ln2_g[j];
      s2 += w * ln2_b[j];
    }
    c1[i] = s1;
    c2p[i] = s2 + b1[i];
  }
  if (i < H * D3) {
    int t = i / D3, c = i % D3;
    float s = 0.f;
    for (int d0 = 0; d0 < D; ++d0) s += te_w[t * D + d0] * w_ih[c * D + d0];
    Tg[i] = s;
  }
  if (i < H * BU) { sumH[i] = 0.f; sumH2[i] = 0.f; }
}

// Per-row sums of sem and sem^2 (for ln2 stats split). One wave per row.
__global__ __launch_bounds__(256) void rowstats_kernel(
    const float* __restrict__ sem, float* __restrict__ Ssem,
    float* __restrict__ Ssem2)
{
  const int wid = threadIdx.x >> 6, lane = threadIdx.x & 63;
  const int row = blockIdx.x * 4 + wid;
  const float* p = sem + (size_t)row * D + lane * 8;
  float4 a0 = *(const float4*)p;
  float4 a1 = *(const float4*)(p + 4);
  float s  = a0.x + a0.y + a0.z + a0.w + a1.x + a1.y + a1.z + a1.w;
  float s2 = a0.x*a0.x + a0.y*a0.y + a0.z*a0.z + a0.w*a0.w
           + a1.x*a1.x + a1.y*a1.y + a1.z*a1.z + a1.w*a1.w;
  #pragma unroll
  for (int o = 1; o < 64; o <<= 1) { s += __shfl_xor(s, o); s2 += __shfl_xor(s2, o); }
  if (lane == 0) { Ssem[row] = s; Ssem2[row] = s2; }
}

// ---------------------------------------------------------------------------
// Setup-only NT bf16 GEMM (64x64 tile, single-buffered). MODE 0: +bias.
// ---------------------------------------------------------------------------
template<int MODE>
__global__ __launch_bounds__(256) void gemm64_kernel(
    const u16* __restrict__ A, const u16* __restrict__ Bw,
    float* __restrict__ C, int ldc, const float* __restrict__ bias)
{
  __shared__ __align__(16) char smem[64 * 128 + 64 * 128];
  char* As = smem;
  char* Bs = smem + 64 * 128;
  const int tid = threadIdx.x, wid = tid >> 6, lane = tid & 63;
  const int wr = wid >> 1, wc = wid & 1;
  const int row0 = blockIdx.x * 64, col0 = blockIdx.y * 64;

  f32x4 acc[2][2] = {};

  for (int kt = 0; kt < 8; ++kt) {
    __syncthreads();
    const int k0 = kt * 64;
    #pragma unroll
    for (int it = 0; it < 2; ++it) {
      int s = it * 256 + tid;
      int pr = s >> 3, pc = s & 7;
      int lch = pc ^ (pr & 7);
      gload_lds16(A + (size_t)(row0 + pr) * D + k0 + lch * 8,
                  As + it * 4096 + wid * 1024);
    }
    #pragma unroll
    for (int it = 0; it < 2; ++it) {
      int s = it * 256 + tid;
      int pr = s >> 3, pc = s & 7;
      int lch = pc ^ (pr & 7);
      gload_lds16(Bw + (size_t)(col0 + pr) * D + k0 + lch * 8,
                  Bs + it * 4096 + wid * 1024);
    }
    asm volatile("s_waitcnt vmcnt(0)" ::: "memory");
    __syncthreads();

    #pragma unroll
    for (int kk = 0; kk < 2; ++kk) {
      const int lc = lane & 15, hi = lane >> 4;
      const int ch = kk * 4 + hi;
      bf16x8 af[2], bfr[2];
      #pragma unroll
      for (int mi = 0; mi < 2; ++mi) {
        int r = wr * 32 + mi * 16 + lc;
        af[mi] = *(const bf16x8*)(As + r * 128 + ((ch ^ (r & 7)) << 4));
      }
      #pragma unroll
      for (int ni = 0; ni < 2; ++ni) {
        int r = wc * 32 + ni * 16 + lc;
        bfr[ni] = *(const bf16x8*)(Bs + r * 128 + ((ch ^ (r & 7)) << 4));
      }
      #pragma unroll
      for (int mi = 0; mi < 2; ++mi)
        #pragma unroll
        for (int ni = 0; ni < 2; ++ni)
          acc[mi][ni] = mfma16(af[mi], bfr[ni], acc[mi][ni]);
    }
  }

  const int lj = lane >> 4, lc2 = lane & 15;
  #pragma unroll
  for (int mi = 0; mi < 2; ++mi)
    #pragma unroll
    for (int ni = 0; ni < 2; ++ni)
      #pragma unroll
      for (int j = 0; j < 4; ++j) {
        int row = row0 + wr * 32 + mi * 16 + lj * 4 + j;
        int col = col0 + wc * 32 + ni * 16 + lc2;
        float v = acc[mi][ni][j];
        if constexpr (MODE == 0) C[(size_t)row * ldc + col] = v + bias[col];
        else                     C[(size_t)row * ldc + col] = v;
      }
}

// ---------------------------------------------------------------------------
// GRU step, 32x64 tile (grid 64x8 = 512 blocks = 2/CU), double-buffered.
// Epilogue: gate math, h/hbf writes, atomic Σh, Σh² per row (ln1 stats).
// ---------------------------------------------------------------------------
__global__ __launch_bounds__(256) void gru2_kernel(
    const u16* __restrict__ hbf_in, const u16* __restrict__ whh_bf,
    const float* __restrict__ G0, const float* __restrict__ Tg,
    const float* __restrict__ b_hh, float* __restrict__ h,
    u16* __restrict__ hbf_out, float* __restrict__ sumH,
    float* __restrict__ sumH2, int t)
{
  constexpr int BUFB = 28672;  // 4 KB A + 24 KB B
  __shared__ __align__(16) char smem[2 * BUFB];  // 56 KB -> 2 blocks/CU
  const int tid = threadIdx.x, wid = tid >> 6, lane = tid & 63;
  const int wr = wid >> 1, wc = wid & 1;
  const int row0 = blockIdx.x * 32, c0 = blockIdx.y * 64;

  f32x4 acc[6] = {};

  auto stage = [&](int b, int kt) {
    char* As = smem + b * BUFB;
    char* Bs = As + 4096;
    {
      int pr = tid >> 3, pc = tid & 7;
      int lch = pc ^ (pr & 7);
      gload_lds16(hbf_in + (size_t)(row0 + pr) * D + kt * 64 + lch * 8,
                  As + wid * 1024);
    }
    #pragma unroll
    for (int it = 0; it < 6; ++it) {
      int s = it * 256 + tid;
      int pr = s >> 3, pc = s & 7;
      int lch = pc ^ (pr & 7);
      int g = pr >> 6, lr = pr & 63;
      gload_lds16(whh_bf + (size_t)(g * D + c0 + lr) * D + kt * 64 + lch * 8,
                  Bs + it * 4096 + wid * 1024);
    }
  };

  stage(0, 0);
  __syncthreads();
  int buf = 0;
  for (int kt = 0; kt < 8; ++kt) {
    if (kt < 7) stage(buf ^ 1, kt + 1);
    const char* As = smem + buf * BUFB;
    const char* Bs = As + 4096;
    const int lc = lane & 15, hi = lane >> 4;
    #pragma unroll
    for (int kk = 0; kk < 2; ++kk) {
      int ch = kk * 4 + hi;
      int ra = wr * 16 + lc;
      bf16x8 af = *(const bf16x8*)(As + ra * 128 + ((ch ^ (ra & 7)) << 4));
      #pragma unroll
      for (int g = 0; g < 3; ++g)
        #pragma unroll
        for (int ci = 0; ci < 2; ++ci) {
          int rb = g * 64 + wc * 32 + ci * 16 + lc;
          bf16x8 bb = *(const bf16x8*)(Bs + rb * 128 + ((ch ^ (rb & 7)) << 4));
          acc[g * 2 + ci] = mfma16(af, bb, acc[g * 2 + ci]);
        }
    }
    __syncthreads();
    buf ^= 1;
  }

  const int lj = lane >> 4, lc2 = lane & 15;
  #pragma unroll
  for (int j = 0; j < 4; ++j) {
    int row = row0 + wr * 16 + lj * 4 + j;
    float hv[2];
    #pragma unroll
    for (int ci = 0; ci < 2; ++ci) {
      int col = c0 + wc * 32 + ci * 16 + lc2;
      float ar = acc[ci][j], az = acc[2 + ci][j], an = acc[4 + ci][j];
      size_t g0i = (size_t)row * D3 + col;
      float gr = G0[g0i]        + Tg[t * D3 + col];
      float gz = G0[g0i + 512]  + Tg[t * D3 + 512 + col];
      float gn = G0[g0i + 1024] + Tg[t * D3 + 1024 + col];
      float r = sigm(gr + ar + b_hh[col]);
      float z = sigm(gz + az + b_hh[512 + col]);
      float n = tanhf(gn + r * (an + b_hh[1024 + col]));
      size_t hi_ = (size_t)row * D + col;
      float ho = h[hi_];
      float hnew = (1.f - z) * n + z * ho;
      h[hi_] = hnew;
      hbf_out[hi_] = f2bf(hnew);
      hv[ci] = hnew;
    }
    float s = hv[0] + hv[1], s2 = hv[0] * hv[0] + hv[1] * hv[1];
    #pragma unroll
    for (int o = 1; o < 16; o <<= 1) {
      s += __shfl_xor(s, o); s2 += __shfl_xor(s2, o);
    }
    if (lc2 == 0) {
      atomicAdd(&sumH [t * BU + row], s);
      atomicAdd(&sumH2[t * BU + row], s2);
    }
  }
}

// ---------------------------------------------------------------------------
// hid GEMM with fused LN1-on-A-load + dyn write + block-local ln2 stats.
// A = ln(h) computed on the fly (reg-staged, swizzled ds_write); B = W1h.
// ---------------------------------------------------------------------------
__global__ __launch_bounds__(256) void lngemm_kernel(
    const float* __restrict__ h, const u16* __restrict__ W1h,
    const float* __restrict__ ln_g, const float* __restrict__ ln_b,
    const float* __restrict__ sumH, const float* __restrict__ sumH2,
    const float* __restrict__ Ssem, const float* __restrict__ Ssem2,
    const float* __restrict__ Psem, const float* __restrict__ c1v,
    const float* __restrict__ c2pv, u16* __restrict__ hid_bf,
    float* __restrict__ dyn_out, int t)
{
  constexpr int ABYTES = 4096, BUFB = ABYTES + 8192;
  __shared__ __align__(16) char smem[2 * BUFB];  // 24 KB
  __shared__ float st_m2[32], st_rs2[32];
  const int tid = threadIdx.x, wid = tid >> 6, lane = tid & 63;
  const int wr = wid >> 1, wc = wid & 1;
  const int row0 = blockIdx.x * 32, col0 = blockIdx.y * 64;
  const int rs = tid >> 3, pc = tid & 7;
  const int grow = row0 + rs;

  float m1 = sumH[t * BU + grow] * (1.f / 512.f);
  float v1 = sumH2[t * BU + grow] * (1.f / 512.f) - m1 * m1;
  float rsd1 = rsqrtf(v1 + 1e-5f);

  float sh = 0.f, sh2 = 0.f;
  float hreg[8];

  auto loadA = [&](int kt) {
    const float* p = h + (size_t)grow * D + kt * 64 + pc * 8;
    float4 a0 = *(const float4*)p, a1 = *(const float4*)(p + 4);
    hreg[0] = a0.x; hreg[1] = a0.y; hreg[2] = a0.z; hreg[3] = a0.w;
    hreg[4] = a1.x; hreg[5] = a1.y; hreg[6] = a1.z; hreg[7] = a1.w;
  };
  auto procA = [&](int b, int kt) {
    int cb = kt * 64 + pc * 8;
    float4 g0 = *(const float4*)(ln_g + cb), g1 = *(const float4*)(ln_g + cb + 4);
    float4 b0 = *(const float4*)(ln_b + cb), b1 = *(const float4*)(ln_b + cb + 4);
    float gg[8] = {g0.x, g0.y, g0.z, g0.w, g1.x, g1.y, g1.z, g1.w};
    float bb[8] = {b0.x, b0.y, b0.z, b0.w, b1.x, b1.y, b1.z, b1.w};
    float hn[8];
    #pragma unroll
    for (int k = 0; k < 8; ++k) {
      float x = (hreg[k] - m1) * rsd1 * gg[k] + bb[k];
      hn[k] = x; sh += x; sh2 += x * x;
    }
    if (blockIdx.y == 0) {
      float* dp = dyn_out + ((size_t)grow * H + t) * D + cb;
      *(float4*)dp       = make_float4(hn[0], hn[1], hn[2], hn[3]);
      *(float4*)(dp + 4) = make_float4(hn[4], hn[5], hn[6], hn[7]);
    }
    union { u16 us[8]; uint4 u; } pk;
    #pragma unroll
    for (int k = 0; k < 8; ++k) pk.us[k] = f2bf(hn[k]);
    *(uint4*)(smem + b * BUFB + rs * 128 + ((pc ^ (rs & 7)) << 4)) = pk.u;
  };
  auto stageB = [&](int b, int kt) {
    char* Bs = smem + b * BUFB + ABYTES;
    #pragma unroll
    for (int it = 0; it < 2; ++it) {
      int s = it * 256 + tid;
      int pr = s >> 3, pcc = s & 7;
      int lch = pcc ^ (pr & 7);
      gload_lds16(W1h + (size_t)(col0 + pr) * D + kt * 64 + lch * 8,
                  Bs + it * 4096 + wid * 1024);
    }
  };

  stageB(0, 0);
  loadA(0);
  procA(0, 0);
  __syncthreads();
  int buf = 0;
  f32x4 acc[2] = {};
  for (int kt = 0; kt < 8; ++kt) {
    if (kt < 7) { stageB(buf ^ 1, kt + 1); loadA(kt + 1); }
    const char* As = smem + buf * BUFB;
    const char* Bs = As + ABYTES;
    const int lc = lane & 15, hi = lane >> 4;
    #pragma unroll
    for (int kk = 0; kk < 2; ++kk) {
      int ch = kk * 4 + hi;
      int ra = wr * 16 + lc;
      bf16x8 af = *(const bf16x8*)(As + ra * 128 + ((ch ^ (ra & 7)) << 4));
      #pragma unroll
      for (int ci = 0; ci < 2; ++ci) {
        int rb = wc * 32 + ci * 16 + lc;
        bf16x8 bb = *(const bf16x8*)(Bs + rb * 128 + ((ch ^ (rb & 7)) << 4));
        acc[ci] = mfma16(af, bb, acc[ci]);
      }
    }
    if (kt < 7) procA(buf ^ 1, kt + 1);
    __syncthreads();
    buf ^= 1;
  }

  // block-local ln2 stats (each block saw the full rows of its A-tile)
  #pragma unroll
  for (int o = 1; o < 8; o <<= 1) { sh += __shfl_xor(sh, o); sh2 += __shfl_xor(sh2, o); }
  if (pc == 0) {
    float m2 = (Ssem[grow] + sh) * (1.f / 1024.f);
    float vv = (Ssem2[grow] + sh2) * (1.f / 1024.f) - m2 * m2;
    st_m2[rs] = m2;
    st_rs2[rs] = rsqrtf(vv + 1e-5f);
  }
  __syncthreads();

  const int lj = lane >> 4, lc2 = lane & 15;
  #pragma unroll
  for (int ci = 0; ci < 2; ++ci)
    #pragma unroll
    for (int j = 0; j < 4; ++j) {
      int lrow = wr * 16 + lj * 4 + j;
      int row = row0 + lrow;
      int col = col0 + wc * 32 + ci * 16 + lc2;
      float m2 = st_m2[lrow], rs2 = st_rs2[lrow];
      float pre = rs2 * (Psem[(size_t)row * D + col] + acc[ci][j])
                  - m2 * rs2 * c1v[col] + c2pv[col];
      float gl = 0.5f * pre * (1.f + erff(pre * 0.70710678118654752f));
      hid_bf[(size_t)row * D + col] = f2bf(gl);
    }
}

// ---------------------------------------------------------------------------
// sems GEMM: out_sems = sem + hid @ w2.T + b2. 32x64 tile, double-buffered.
// ---------------------------------------------------------------------------
__global__ __launch_bounds__(256) void semgemm_kernel(
    const u16* __restrict__ hid_bf, const u16* __restrict__ w2bf,
    const float* __restrict__ z_sem, const float* __restrict__ b2,
    float* __restrict__ out_sems, int t)
{
  constexpr int ABYTES = 4096, BUFB = ABYTES + 8192;
  __shared__ __align__(16) char smem[2 * BUFB];
  const int tid = threadIdx.x, wid = tid >> 6, lane = tid & 63;
  const int wr = wid >> 1, wc = wid & 1;
  const int row0 = blockIdx.x * 32, col0 = blockIdx.y * 64;

  auto stage = [&](int b, int kt) {
    char* As = smem + b * BUFB;
    char* Bs = As + ABYTES;
    {
      int pr = tid >> 3, pcc = tid & 7;
      int lch = pcc ^ (pr & 7);
      gload_lds16(hid_bf + (size_t)(row0 + pr) * D + kt * 64 + lch * 8,
                  As + wid * 1024);
    }
    #pragma unroll
    for (int it = 0; it < 2; ++it) {
      int s = it * 256 + tid;
      int pr = s >> 3, pcc = s & 7;
      int lch = pcc ^ (pr & 7);
      gload_lds16(w2bf + (size_t)(col0 + pr) * D + kt * 64 + lch * 8,
                  Bs + it * 4096 + wid * 1024);
    }
  };

  stage(0, 0);
  __syncthreads();
  int buf = 0;
  f32x4 acc[2] = {};
  for (int kt = 0; kt < 8; ++kt) {
    if (kt < 7) stage(buf ^ 1, kt + 1);
    const char* As = smem + buf * BUFB;
    const char* Bs = As + ABYTES;
    const int lc = lane & 15, hi = lane >> 4;
    #pragma unroll
    for (int kk = 0; kk < 2; ++kk) {
      int ch = kk * 4 + hi;
      int ra = wr * 16 + lc;
      bf16x8 af = *(const bf16x8*)(As + ra * 128 + ((ch ^ (ra & 7)) << 4));
      #pragma unroll
      for (int ci = 0; ci < 2; ++ci) {
        int rb = wc * 32 + ci * 16 + lc;
        bf16x8 bb = *(const bf16x8*)(Bs + rb * 128 + ((ch ^ (rb & 7)) << 4));
        acc[ci] = mfma16(af, bb, acc[ci]);
      }
    }
    __syncthreads();
    buf ^= 1;
  }

  const int lj = lane >> 4, lc2 = lane & 15;
  #pragma unroll
  for (int ci = 0; ci < 2; ++ci)
    #pragma unroll
    for (int j = 0; j < 4; ++j) {
      int row = row0 + wr * 16 + lj * 4 + j;
      int col = col0 + wc * 32 + ci * 16 + lc2;
      out_sems[((size_t)row * H + t) * D + col] =
          z_sem[(size_t)row * D + col] + acc[ci][j] + b2[col];
    }
}

// ---------------------------------------------------------------------------
extern "C" void kernel_launch(void* const* d_in, const int* in_sizes, int n_in,
                              void* d_out, int out_size, void* d_ws, size_t ws_size,
                              hipStream_t stream)
{
  (void)in_sizes; (void)n_in; (void)out_size; (void)ws_size;
  const float* z_dyn = (const float*)d_in[0];
  const float* z_sem = (const float*)d_in[1];
  const float* te_w  = (const float*)d_in[2];
  const float* w_ih  = (const float*)d_in[3];
  const float* w_hh  = (const float*)d_in[4];
  const float* b_ih  = (const float*)d_in[5];
  const float* b_hh  = (const float*)d_in[6];
  const float* ln_g  = (const float*)d_in[7];
  const float* ln_b  = (const float*)d_in[8];
  const float* ln2_g = (const float*)d_in[9];
  const float* ln2_b = (const float*)d_in[10];
  const float* w1    = (const float*)d_in[11];
  const float* b1    = (const float*)d_in[12];
  const float* w2    = (const float*)d_in[13];
  const float* b2    = (const float*)d_in[14];

  char* ws = (char*)d_ws;
  const size_t MB = 1ull << 20;
  float* h      = (float*)(ws + 0);
  u16*  hbf0    = (u16*)(ws + 4 * MB);
  u16*  hbf1    = (u16*)(ws + 6 * MB);
  float* G0     = (float*)(ws + 8 * MB);
  float* Tg     = (float*)(ws + 20 * MB);
  float* Psem   = (float*)(ws + 21 * MB);
  u16*  sem_bf  = (u16*)(ws + 25 * MB);
  u16*  hid_bf  = (u16*)(ws + 27 * MB);
  u16*  wih_bf  = (u16*)(ws + 29 * MB);
  u16*  whh_bf  = (u16*)(ws + 31 * MB);
  u16*  W1s     = (u16*)(ws + 33 * MB);
  u16*  W1h     = (u16*)(ws + 34 * MB);
  u16*  w2bf    = (u16*)(ws + 35 * MB);
  float* c1     = (float*)(ws + 36 * MB);
  float* c2p    = (float*)(ws + 36 * MB + 4096);
  float* Ssem   = (float*)(ws + 36 * MB + 16384);
  float* Ssem2  = (float*)(ws + 36 * MB + 32768);
  float* sumH   = (float*)(ws + 37 * MB);
  float* sumH2  = (float*)(ws + 37 * MB + 512 * 1024);

  float* outp = (float*)d_out;
  float* out_dyn  = outp;
  float* out_sems = outp + OUT_HALF;

  prep_kernel<<<4096, 256, 0, stream>>>(
      z_dyn, z_sem, te_w, w_ih, w_hh, ln2_g, ln2_b, w1, b1, w2,
      h, hbf0, sem_bf, wih_bf, whh_bf, W1s, W1h, w2bf, c1, c2p, Tg,
      sumH, sumH2);
  rowstats_kernel<<<512, 256, 0, stream>>>(z_sem, Ssem, Ssem2);

  gemm64_kernel<0><<<dim3(32, 24), 256, 0, stream>>>(
      sem_bf, wih_bf, G0, D3, b_ih);
  gemm64_kernel<1><<<dim3(32, 8), 256, 0, stream>>>(
      sem_bf, W1s, Psem, D, nullptr);

  for (int t = 0; t < H; ++t) {
    const u16* hin = (t & 1) ? hbf1 : hbf0;
    u16* hout      = (t & 1) ? hbf0 : hbf1;
    gru2_kernel<<<dim3(64, 8), 256, 0, stream>>>(
        hin, whh_bf, G0, Tg, b_hh, h, hout, sumH, sumH2, t);
    lngemm_kernel<<<dim3(64, 8), 256, 0, stream>>>(
        h, W1h, ln_g, ln_b, sumH, sumH2, Ssem, Ssem2,
        Psem, c1, c2p, hid_bf, out_dyn, t);
    semgemm_kernel<<<dim3(64, 8), 256, 0, stream>>>(
        hid_bf, w2bf, z_sem, b2, out_sems, t);
  }
}